// Round 9
// baseline (500.507 us; speedup 1.0000x reference)
//
#include <hip/hip_runtime.h>
#include <math.h>

// Problem constants
#define BB 4
#define TT 2048
#define DD 1024
#define HH 16
#define QKD 64
#define MM (BB*TT)          // 8192
#define NN 1024             // H*QK == D
#define KK 1024

// 256x256 GEMM tile geometry
#define BKG 64              // K-step (64 MFMA/wave per barrier-pair)
#define NTSG (KK/BKG)       // 16 k-steps

typedef unsigned short u16;
typedef __attribute__((ext_vector_type(8))) short short8;   // 8 bf16 = 4 VGPRs
typedef __attribute__((ext_vector_type(4))) float float4v;  // MFMA C/D

// fp32 -> bf16 round-to-nearest-even
__device__ __forceinline__ u16 f2bf(float f) {
    union { float f; unsigned u; } v; v.f = f;
    unsigned r = (v.u + 0x7FFFu + ((v.u >> 16) & 1u)) >> 16;
    return (u16)r;
}

// packed fp32x2 -> bf16x2 (RTNE), single instruction on gfx950
__device__ __forceinline__ unsigned cvt_pk_bf16(float lo, float hi) {
    unsigned r;
    asm("v_cvt_pk_bf16_f32 %0, %1, %2" : "=v"(r) : "v"(lo), "v"(hi));
    return r;
}

// async global->LDS, 16B per lane; LDS dest = wave-uniform base + lane*16
typedef __attribute__((address_space(3))) unsigned lds_u32_t;
typedef __attribute__((address_space(1))) const unsigned glb_u32_t;
__device__ __forceinline__ void gl2lds16(const u16* g, u16* l) {
    __builtin_amdgcn_global_load_lds((glb_u32_t*)g, (lds_u32_t*)l, 16, 0, 0);
}

// Conflict-free slot swizzle for 8-slot (128B) rows read as ds_read_b128 with
// row = base + l15, slot = kk*4 + lg: LDS slot s' of row r holds global
// colblock s' ^ g(r), g(r) = (j&1) | ((j&2)*3), j = (r>>2)&3.  Enumeration:
// each b128 wave-read lands exactly 2 lanes per 32B bank-granule (free, m136).
__device__ __forceinline__ int swz_slot(int row, int slot) {
    const int j = (row >> 2) & 3;
    return slot ^ ((j & 1) | ((j & 2) * 3));
}

// ---------------------------------------------------------------------------
// fp32 -> bf16 cast for activations (q, kv)
// ---------------------------------------------------------------------------
__global__ __launch_bounds__(256) void acast_kernel(
    const float* __restrict__ a, const float* __restrict__ b,
    u16* __restrict__ da, u16* __restrict__ db)
{
    const float* s = blockIdx.y ? b : a;
    u16* d = blockIdx.y ? db : da;
    size_t i = ((size_t)blockIdx.x * 256 + threadIdx.x) * 4;
    float4 v = *(const float4*)&s[i];
    ushort4 o = { f2bf(v.x), f2bf(v.y), f2bf(v.z), f2bf(v.w) };
    *(ushort4*)&d[i] = o;
}

// ---------------------------------------------------------------------------
// Weight transpose + cast: W[K][N] fp32 -> Wt[N][K] bf16, z selects matrix
// ---------------------------------------------------------------------------
__global__ __launch_bounds__(256) void wt_kernel(
    const float* __restrict__ Wq, const float* __restrict__ Wk,
    const float* __restrict__ Wv, const float* __restrict__ Wo,
    u16* __restrict__ dstbase)
{
    const int z = blockIdx.z;
    const float* src = (z == 0) ? Wq : (z == 1) ? Wk : (z == 2) ? Wv : Wo;
    u16* out = dstbase + (size_t)z * (KK * NN);
    const int bi = blockIdx.y, bj = blockIdx.x;  // 64x64 tile: k-block, n-block
    __shared__ float tile[64][65];
    const int t = threadIdx.x;
    #pragma unroll
    for (int p = 0; p < 4; p++) {
        int idx = p * 256 + t;
        int r = idx >> 4, c4 = (idx & 15) << 2;
        float4 v = *(const float4*)&src[(size_t)(bi * 64 + r) * NN + bj * 64 + c4];
        tile[r][c4 + 0] = v.x; tile[r][c4 + 1] = v.y;
        tile[r][c4 + 2] = v.z; tile[r][c4 + 3] = v.w;
    }
    __syncthreads();
    #pragma unroll
    for (int p = 0; p < 4; p++) {
        int idx = p * 256 + t;
        int rn = idx >> 4, c4 = (idx & 15) << 2;
        ushort4 o = { f2bf(tile[c4 + 0][rn]), f2bf(tile[c4 + 1][rn]),
                      f2bf(tile[c4 + 2][rn]), f2bf(tile[c4 + 3][rn]) };
        *(ushort4*)&out[(size_t)(bj * 64 + rn) * KK + bi * 64 + c4] = o;
    }
}

// ---------------------------------------------------------------------------
// 256x256 bf16 MFMA GEMM mainloop, v3: BK=64 per step (64 MFMA/wave per
// barrier-pair, 16 steps), double-buffered 128KB LDS.  8 waves (512 thr),
// wave grid 2(m)x4(n), per-wave output 128x64 = acc[8][4].  gl_lds staging
// with pre-swizzled global source (swz_slot above), linear LDS dest.
// Pipeline: issue tile t+1 (8 loads/thread) at START of step t -> one full
// step of latency cover; counted vmcnt(8) (drain-0 only at tail).  Buffer
// safety: reads of buf are register-consumed (lgkmcnt before MFMA) before
// the trailing barrier, and t+2's issue into buf happens after it.
// A: [M,K] bf16 row-major.  Bt: [N,K] bf16 row-major (i.e. W^T).
// sh: 128KB u16[65536]: buf b at sh + b*32768 (A 16384 u16, then B 16384).
// ---------------------------------------------------------------------------
__device__ __forceinline__ void gemm256_mainloop(
    const u16* __restrict__ A, const u16* __restrict__ Bt,
    int m0, int n0, u16* __restrict__ sh, float4v (&acc)[8][4])
{
    const int tid = threadIdx.x;          // 0..511
    const int lane = tid & 63;
    const int l15 = lane & 15, lg = lane >> 4;
    const int wave = tid >> 6;
    const int wm = wave >> 2, wn = wave & 3;

    // staging: per matrix 2048 16B-chunks (256 rows x 8 slots); this thread
    // handles chunks tid + i*512 (i=0..3) for A and for B.
    const u16* gA[4]; const u16* gB[4]; int ld_off[4];
    #pragma unroll
    for (int i = 0; i < 4; i++) {
        const int c = tid + i * 512;
        const int r = c >> 3, sp = c & 7;
        const int gs = swz_slot(r, sp);          // pre-swizzled global colblock
        gA[i] = A  + (size_t)(m0 + r) * KK + gs * 8;
        gB[i] = Bt + (size_t)(n0 + r) * KK + gs * 8;
        ld_off[i] = c * 8;                       // linear LDS dest (u16 units)
    }

    auto issue = [&](int buf, int k0) {          // 8 gl_lds per thread
        u16* dA = sh + buf * 32768;
        u16* dB = dA + 16384;
        #pragma unroll
        for (int i = 0; i < 4; i++) gl2lds16(gA[i] + k0, dA + ld_off[i]);
        #pragma unroll
        for (int i = 0; i < 4; i++) gl2lds16(gB[i] + k0, dB + ld_off[i]);
    };

    issue(0, 0);                                 // tile 0 -> buf0

    for (int t = 0; t < NTSG; t++) {
        const int buf = t & 1;
        if (t + 1 < NTSG) {
            issue(buf ^ 1, (t + 1) * BKG);       // prefetch next tile
            asm volatile("s_waitcnt vmcnt(8)" ::: "memory");   // tile t landed
        } else {
            asm volatile("s_waitcnt vmcnt(0)" ::: "memory");   // tail drain
        }
        __builtin_amdgcn_s_barrier();            // tile t visible to ALL waves
        __builtin_amdgcn_sched_barrier(0);

        const u16* cA = sh + buf * 32768;
        const u16* cB = cA + 16384;

        #pragma unroll
        for (int kk = 0; kk < 2; kk++) {
            short8 af[8], bf[4];
            #pragma unroll
            for (int x = 0; x < 8; x++) {
                const int ra = wm * 128 + x * 16 + l15;
                af[x] = *(const short8*)(cA + ra * 64 + swz_slot(ra, kk * 4 + lg) * 8);
            }
            #pragma unroll
            for (int x = 0; x < 4; x++) {
                const int rb = wn * 64 + x * 16 + l15;
                bf[x] = *(const short8*)(cB + rb * 64 + swz_slot(rb, kk * 4 + lg) * 8);
            }
            __builtin_amdgcn_s_setprio(1);
            #pragma unroll
            for (int mi = 0; mi < 8; mi++)
                #pragma unroll
                for (int nj = 0; nj < 4; nj++)
                    acc[mi][nj] = __builtin_amdgcn_mfma_f32_16x16x32_bf16(af[mi], bf[nj], acc[mi][nj], 0, 0, 0);
            __builtin_amdgcn_s_setprio(0);
        }

        __builtin_amdgcn_s_barrier();   // close reads of buf before t+2 issue
        __builtin_amdgcn_sched_barrier(0);
    }
}

// XCD band swizzle for a 4(n) x 32(m) grid: flat -> (m_idx, n_idx) so each
// XCD owns a contiguous band of 4 m-rows x all 4 n-tiles (A 2MB + B 2MB fits
// the 4MB per-XCD L2).  Bijective (128 = 8 x 16).
__device__ __forceinline__ void xcd_swizzle_4x32(int& m_idx, int& n_idx) {
    const int flat = blockIdx.y * 4 + blockIdx.x;   // 0..127
    const int xcd = flat & 7, q = flat >> 3;        // q: 0..15
    m_idx = xcd * 4 + (q & 3);                      // 0..31
    n_idx = q >> 2;                                 // 0..3
}

// ---------------------------------------------------------------------------
// QKV projection GEMM (256^2 tile), z in {0:Q, 1:K, 2:V}.
// Q,K: bias + RMSNorm + RoPE -> (B,H,T,QK) bf16 (Q also * 0.125*log2e).
// V:   bias -> transposed (B,H,QK,T) bf16.
// Epilogue stores route through the (now free) LDS in two 128-row passes so
// every global store instruction writes full 128B lines.
// ---------------------------------------------------------------------------
__global__ __launch_bounds__(512, 2) void qkv_gemm(
    const u16* __restrict__ qb, const u16* __restrict__ kvb,
    const u16* __restrict__ Wt,
    const float* __restrict__ bq, const float* __restrict__ bk, const float* __restrict__ bv,
    const int* __restrict__ qpos, const int* __restrict__ kpos,
    const float* __restrict__ q_scale, const float* __restrict__ k_scale,
    u16* __restrict__ qh, u16* __restrict__ kh, u16* __restrict__ vt)
{
    __shared__ __align__(16) u16 sh[65536];   // 128 KB: 2-buf staging, then epilogue stash

    const int z = blockIdx.z;
    const u16* A        = (z == 0) ? qb : kvb;
    const u16* B        = Wt + (size_t)z * (KK * NN);
    const float* bias   = (z == 0) ? bq : (z == 1) ? bk : bv;
    const float* scl    = (z == 0) ? q_scale : k_scale;
    const int* pos_arr  = (z == 0) ? qpos : kpos;
    u16* dst            = (z == 0) ? qh : (z == 1) ? kh : vt;

    int m_idx, n_idx;
    xcd_swizzle_4x32(m_idx, n_idx);
    const int m0 = m_idx * 256, n0 = n_idx * 256;

    float4v acc[8][4];
    #pragma unroll
    for (int i = 0; i < 8; i++)
        #pragma unroll
        for (int j = 0; j < 4; j++) acc[i][j] = (float4v){0.f, 0.f, 0.f, 0.f};

    gemm256_mainloop(A, B, m0, n0, sh, acc);

    const int tid = threadIdx.x;
    const int lane = tid & 63, wave = tid >> 6;
    const int l15 = lane & 15, lg = lane >> 4;
    const int wm = wave >> 2, wn = wave & 3;

    float bia[4], sc[4];
    #pragma unroll
    for (int nj = 0; nj < 4; nj++) {
        bia[nj] = bias[n0 + wn * 64 + nj * 16 + l15];
        sc[nj]  = 1.0f + scl[nj * 16 + l15];
    }
    float invts[2];
    #pragma unroll
    for (int p = 0; p < 2; p++)
        invts[p] = powf(10000.0f, -(float)(p * 16 + l15) * (1.0f / 32.0f));

    const float QMUL = 0.125f * 1.44269504088896340736f;
    const int bb_ = m0 >> 11;       // batch (tile never straddles a batch)
    const int t0g = m0 & 2047;      // global t base of this tile

    if (z < 2) {
        // ---- Q/K epilogue: two passes of 128 rows through the LDS stash ----
        #pragma unroll
        for (int p = 0; p < 2; p++) {
            __syncthreads();
            if (wm == p) {
                #pragma unroll
                for (int mi = 0; mi < 8; mi++) {
                    #pragma unroll
                    for (int r = 0; r < 4; r++) {
                        const int tl = mi * 16 + lg * 4 + r;      // 0..127
                        const int m = m0 + p * 128 + tl;
                        const int b = m >> 11, t = m & 2047;
                        float v[4];
                        #pragma unroll
                        for (int nj = 0; nj < 4; nj++) v[nj] = acc[mi][nj][r] + bia[nj];

                        float ss = v[0]*v[0] + v[1]*v[1] + v[2]*v[2] + v[3]*v[3];
                        ss += __shfl_xor(ss, 1);
                        ss += __shfl_xor(ss, 2);
                        ss += __shfl_xor(ss, 4);
                        ss += __shfl_xor(ss, 8);
                        float rn = rsqrtf(ss * (1.0f / 64.0f) + 1e-6f);
                        #pragma unroll
                        for (int nj = 0; nj < 4; nj++) v[nj] = v[nj] * rn * sc[nj];

                        const float pos = (float)pos_arr[b * TT + t];
                        #pragma unroll
                        for (int pp = 0; pp < 2; pp++) {
                            float ang = pos * invts[pp];
                            float s = sinf(ang), c = cosf(ang);
                            float x1 = v[pp], x2 = v[pp + 2];
                            v[pp]     = x1 * c - x2 * s;
                            v[pp + 2] = x2 * c + x1 * s;
                        }
                        if (z == 0) {
                            #pragma unroll
                            for (int nj = 0; nj < 4; nj++) v[nj] *= QMUL;
                        }
                        #pragma unroll
                        for (int nj = 0; nj < 4; nj++) {
                            const int dl = wn * 64 + nj * 16 + l15;   // 0..255
                            sh[tl * 256 + (dl ^ ((tl & 7) << 3))] = f2bf(v[nj]);
                        }
                    }
                }
            }
            __syncthreads();
            // cooperative coalesced store of rows p*128..p*128+127
            #pragma unroll
            for (int it = 0; it < 8; it++) {
                int idx = it * 512 + tid;       // 0..4095
                int tl  = idx >> 5;             // 0..127
                int c8  = (idx & 31) << 3;      // 0..248 step 8
                short8 v8 = *(const short8*)&sh[tl * 256 + (c8 ^ ((tl & 7) << 3))];
                int cg = n0 + c8;
                int hh_ = cg >> 6, dih = cg & 63;
                int t = t0g + p * 128 + tl;
                *(short8*)&dst[((size_t)(bb_ * HH + hh_) * TT + t) * QKD + dih] = v8;
            }
        }
    } else {
        // ---- V epilogue: transposed stash [256 d][128 t] per pass ----
        #pragma unroll
        for (int p = 0; p < 2; p++) {
            __syncthreads();
            if (wm == p) {
                #pragma unroll
                for (int mi = 0; mi < 8; mi++) {
                    #pragma unroll
                    for (int r = 0; r < 4; r++) {
                        const int tl = mi * 16 + lg * 4 + r;      // 0..127
                        #pragma unroll
                        for (int nj = 0; nj < 4; nj++) {
                            const int dl = wn * 64 + nj * 16 + l15;   // 0..255
                            sh[dl * 128 + (tl ^ ((dl & 7) << 3))] = f2bf(acc[mi][nj][r] + bia[nj]);
                        }
                    }
                }
            }
            __syncthreads();
            #pragma unroll
            for (int it = 0; it < 8; it++) {
                int idx = it * 512 + tid;       // 0..4095
                int dl  = idx >> 4;             // 0..255
                int tc  = (idx & 15) << 3;      // 0..120 step 8
                short8 v8 = *(const short8*)&sh[dl * 128 + (tc ^ ((dl & 7) << 3))];
                int dg = n0 + dl;
                int hh_ = dg >> 6, dih = dg & 63;
                *(short8*)&vt[((size_t)(bb_ * HH + hh_) * QKD + dih) * TT + t0g + p * 128 + tc] = v8;
            }
        }
    }
}

// ---------------------------------------------------------------------------
// Output projection GEMM (256^2): attn_b[M,K] bf16 @ Wo_t[N,K]^T + bo -> fp32
// ---------------------------------------------------------------------------
__global__ __launch_bounds__(512, 2) void out_gemm(
    const u16* __restrict__ A, const u16* __restrict__ Bt,
    const float* __restrict__ bo, float* __restrict__ out)
{
    __shared__ __align__(16) u16 sh[65536];

    int m_idx, n_idx;
    xcd_swizzle_4x32(m_idx, n_idx);
    const int m0 = m_idx * 256, n0 = n_idx * 256;

    float4v acc[8][4];
    #pragma unroll
    for (int i = 0; i < 8; i++)
        #pragma unroll
        for (int j = 0; j < 4; j++) acc[i][j] = (float4v){0.f, 0.f, 0.f, 0.f};

    gemm256_mainloop(A, Bt, m0, n0, sh, acc);

    const int lane = threadIdx.x & 63, wave = threadIdx.x >> 6;
    const int l15 = lane & 15, lg = lane >> 4;
    const int wm = wave >> 2, wn = wave & 3;

    float bov[4];
    #pragma unroll
    for (int nj = 0; nj < 4; nj++) bov[nj] = bo[n0 + wn * 64 + nj * 16 + l15];

    #pragma unroll
    for (int mi = 0; mi < 8; mi++)
        #pragma unroll
        for (int r = 0; r < 4; r++) {
            const int m = m0 + wm * 128 + mi * 16 + lg * 4 + r;
            float* op = out + (size_t)m * NN + n0 + wn * 64 + l15;
            #pragma unroll
            for (int nj = 0; nj < 4; nj++)
                op[nj * 16] = acc[mi][nj][r] + bov[nj];
        }
}

// ---------------------------------------------------------------------------
// MFMA flash attention, causal.  PAIRED COMPLEMENTARY Q-TILES (unchanged).
// Block p processes qt_a = p and qt_b = 31-p: per-block work = 33 row-tiles
// (uniform), grid = 16x16x4 = 1024 blocks = exactly 4/CU.  K/V tile jt is
// staged ONCE and consumed by both Q-tiles (qt_b always, qt_a while jt <= p).
// ---------------------------------------------------------------------------
__global__ __launch_bounds__(256) void attn_mfma(
    const u16* __restrict__ qh, const u16* __restrict__ kh,
    const u16* __restrict__ vt, const float* __restrict__ head_scale,
    u16* __restrict__ out)
{
    __shared__ __align__(16) u16 Ks[2][64 * 64];   // K rows (swizzled)
    __shared__ __align__(16) u16 Vs[2][64 * 64];   // V^T rows = d (swizzled)
    __shared__ __align__(16) u16 Ps[4][16 * 64];   // per-wave P tile (swizzled)

    const int b = blockIdx.z, h = blockIdx.y;
    const int qta = blockIdx.x;          // 0..15  (small tile)
    const int qtb = 31 - qta;            // 16..31 (big tile)
    const int t0a = qta * 64, t0b = qtb * 64;

    const int tid  = threadIdx.x;
    const int wave = tid >> 6, lane = tid & 63;
    const int l15 = lane & 15, lg = lane >> 4;
    const int l7 = l15 & 7;

    const size_t bh = (size_t)(b * HH + h);
    const u16* qbh  = qh + bh * TT * QKD;
    const u16* kbh  = kh + bh * TT * QKD;
    const u16* vtbh = vt + bh * QKD * TT;   // [QKD][TT]

    short8 qfA[2], qfB[2];
    #pragma unroll
    for (int kc = 0; kc < 2; kc++) {
        qfA[kc] = *(const short8*)(qbh + (size_t)(t0a + wave * 16 + l15) * QKD
                                    + kc * 32 + lg * 8);
        qfB[kc] = *(const short8*)(qbh + (size_t)(t0b + wave * 16 + l15) * QKD
                                    + kc * 32 + lg * 8);
    }

    auto stage = [&](int buf, int j0s) {
        #pragma unroll
        for (int rr = 0; rr < 2; rr++) {
            const int c   = rr * 256 + tid;     // chunk 0..511 (16B each)
            const int row = c >> 3;             // 0..63
            const int g   = (c & 7) ^ (row & 7);// pre-swizzled global colblock
            u16* ldsK = &Ks[buf][(rr * 256 + (wave << 6)) * 8];
            u16* ldsV = &Vs[buf][(rr * 256 + (wave << 6)) * 8];
            gl2lds16(kbh  + (size_t)(j0s + row) * QKD + g * 8, ldsK);
            gl2lds16(vtbh + (size_t)row * TT + j0s + g * 8, ldsV);
        }
    };

    float4v oA[4], oB[4];
    #pragma unroll
    for (int nt = 0; nt < 4; nt++) {
        oA[nt] = (float4v){0.f, 0.f, 0.f, 0.f};
        oB[nt] = (float4v){0.f, 0.f, 0.f, 0.f};
    }
    float mA[4] = {-INFINITY, -INFINITY, -INFINITY, -INFINITY};
    float mB[4] = {-INFINITY, -INFINITY, -INFINITY, -INFINITY};
    float lA[4] = {0.f, 0.f, 0.f, 0.f};
    float lB[4] = {0.f, 0.f, 0.f, 0.f};

    auto flash_step = [&](int cur, int jt, int qt_self,
                          short8 (&qf)[2], float4v (&oa)[4],
                          float (&mr)[4], float (&lr)[4]) {
        // ---- QK^T (swizzled K reads) ----
        float4v sarr[4];
        #pragma unroll
        for (int nt = 0; nt < 4; nt++) {
            float4v s = (float4v){0.f, 0.f, 0.f, 0.f};
            #pragma unroll
            for (int kc = 0; kc < 2; kc++) {
                const short8 bfrag = *(const short8*)
                    &Ks[cur][(nt * 16 + l15) * 64 + ((kc * 4 + lg) ^ l7) * 8];
                s = __builtin_amdgcn_mfma_f32_16x16x32_bf16(qf[kc], bfrag, s, 0, 0, 0);
            }
            sarr[nt] = s;
        }

        // ---- causal mask (diagonal tile only) ----
        if (jt == qt_self) {
            const int qbase = qt_self * 64 + wave * 16 + lg * 4;
            #pragma unroll
            for (int nt = 0; nt < 4; nt++) {
                int jkey = jt * 64 + nt * 16 + l15;
                #pragma unroll
                for (int r = 0; r < 4; r++)
                    if (jkey > qbase + r) sarr[nt][r] = -INFINITY;
            }
        }

        // ---- row max + defer-max rescale (T13) ----
        float pm[4];
        #pragma unroll
        for (int r = 0; r < 4; r++) {
            float m = fmaxf(fmaxf(sarr[0][r], sarr[1][r]), fmaxf(sarr[2][r], sarr[3][r]));
            m = fmaxf(m, __shfl_xor(m, 1));
            m = fmaxf(m, __shfl_xor(m, 2));
            m = fmaxf(m, __shfl_xor(m, 4));
            m = fmaxf(m, __shfl_xor(m, 8));
            pm[r] = m;
        }
        float grow = fmaxf(fmaxf(pm[0] - mr[0], pm[1] - mr[1]),
                           fmaxf(pm[2] - mr[2], pm[3] - mr[3]));
        if (__any(grow > 8.0f)) {
            #pragma unroll
            for (int r = 0; r < 4; r++) {
                float mn = fmaxf(mr[r], pm[r]);
                float a  = exp2f(mr[r] - mn);
                mr[r] = mn;
                lr[r] *= a;
                #pragma unroll
                for (int nt = 0; nt < 4; nt++) oa[nt][r] *= a;
            }
        }

        // ---- P = exp2(S - m), partial rowsum, packed bf16 store to Ps ----
        u16* pw = Ps[wave];
        float lp[4] = {0.f, 0.f, 0.f, 0.f};
        #pragma unroll
        for (int nt = 0; nt < 4; nt++) {
            float p0 = exp2f(sarr[nt][0] - mr[0]);
            float p1 = exp2f(sarr[nt][1] - mr[1]);
            float p2 = exp2f(sarr[nt][2] - mr[2]);
            float p3 = exp2f(sarr[nt][3] - mr[3]);
            lp[0] += p0; lp[1] += p1; lp[2] += p2; lp[3] += p3;
            unsigned wlo = cvt_pk_bf16(p0, p1);
            unsigned whi = cvt_pk_bf16(p2, p3);
            const int gb = nt * 2 + (l15 >> 3);
            const int r0 = lg * 4;
            pw[(r0 + 0) * 64 + ((gb ^ ((r0 + 0) & 7))) * 8 + l7] = (u16)wlo;
            pw[(r0 + 1) * 64 + ((gb ^ ((r0 + 1) & 7))) * 8 + l7] = (u16)(wlo >> 16);
            pw[(r0 + 2) * 64 + ((gb ^ ((r0 + 2) & 7))) * 8 + l7] = (u16)whi;
            pw[(r0 + 3) * 64 + ((gb ^ ((r0 + 3) & 7))) * 8 + l7] = (u16)(whi >> 16);
        }
        #pragma unroll
        for (int r = 0; r < 4; r++) lr[r] += lp[r];

        // ---- read P fragments back (same wave; lgkmcnt ordered) ----
        short8 pf[2];
        #pragma unroll
        for (int kc = 0; kc < 2; kc++)
            pf[kc] = *(const short8*)&pw[l15 * 64 + ((kc * 4 + lg) ^ l7) * 8];

        // ---- PV (swizzled V^T reads) ----
        #pragma unroll
        for (int nt = 0; nt < 4; nt++) {
            #pragma unroll
            for (int kc = 0; kc < 2; kc++) {
                const short8 vfrag = *(const short8*)
                    &Vs[cur][(nt * 16 + l15) * 64 + ((kc * 4 + lg) ^ l7) * 8];
                oa[nt] = __builtin_amdgcn_mfma_f32_16x16x32_bf16(pf[kc], vfrag, oa[nt], 0, 0, 0);
            }
        }
    };

    stage(0, 0);
    __syncthreads();

    const int njt = qtb + 1;     // jt = 0..qtb
    for (int jt = 0; jt < njt; jt++) {
        const int cur = jt & 1;
        if (jt + 1 < njt) stage(cur ^ 1, (jt + 1) * 64);   // prefetch next tile

        flash_step(cur, jt, qtb, qfB, oB, mB, lB);          // big tile: always
        if (jt <= qta)
            flash_step(cur, jt, qta, qfA, oA, mA, lA);      // small tile: prefix

        __syncthreads();   // drains prefetch vmcnt + protects buffer reuse
    }

    // ---- epilogue: both Q-tiles ----
    const float hs = 1.0f + head_scale[h];
    auto epilogue = [&](int t0, float4v (&oa)[4], float (&lr)[4]) {
        #pragma unroll
        for (int r = 0; r < 4; r++) {
            float l = lr[r];
            l += __shfl_xor(l, 1);
            l += __shfl_xor(l, 2);
            l += __shfl_xor(l, 4);
            l += __shfl_xor(l, 8);
            const int q = t0 + wave * 16 + lg * 4 + r;
            const float f = hs / l;
            u16* op = out + ((size_t)(b * TT + q) * NN) + h * QKD + l15;
            #pragma unroll
            for (int nt = 0; nt < 4; nt++)
                op[nt * 16] = f2bf(oa[nt][r] * f);
        }
    };
    epilogue(t0b, oB, lB);
    epilogue(t0a, oA, lA);
}

// ---------------------------------------------------------------------------
extern "C" void kernel_launch(void* const* d_in, const int* in_sizes, int n_in,
                              void* d_out, int out_size, void* d_ws, size_t ws_size,
                              hipStream_t stream)
{
    const float* q          = (const float*)d_in[0];
    const float* kv         = (const float*)d_in[1];
    /* d_in[2] = causal mask -- handled analytically */
    const int*   qpos       = (const int*)d_in[3];
    const int*   kpos       = (const int*)d_in[4];
    const float* Wq         = (const float*)d_in[5];
    const float* bq         = (const float*)d_in[6];
    const float* Wk         = (const float*)d_in[7];
    const float* bk         = (const float*)d_in[8];
    const float* Wv         = (const float*)d_in[9];
    const float* bv         = (const float*)d_in[10];
    const float* q_scale    = (const float*)d_in[11];
    const float* k_scale    = (const float*)d_in[12];
    const float* head_scale = (const float*)d_in[13];
    const float* Wo         = (const float*)d_in[14];
    const float* bo         = (const float*)d_in[15];
    float* out = (float*)d_out;

    // workspace layout (bytes):
    //   [  0 MB, 16 MB)  qb    (M,K) bf16
    //   [ 16 MB, 32 MB)  kvb   (M,K) bf16
    //   [ 32 MB, 40 MB)  Wt    4 x (N,K) bf16 transposed: Wq,Wk,Wv,Wo
    //   [ 40 MB, 56 MB)  qh_b  (B,H,T,QK) bf16
    //   [ 56 MB, 72 MB)  kh_b  (B,H,T,QK) bf16
    //   [ 72 MB, 88 MB)  vt_b  (B,H,QK,T) bf16  <-- V stored transposed
    //   [ 88 MB,104 MB)  attn_b (B,T,N) bf16
    char* ws = (char*)d_ws;
    u16* qb     = (u16*)(ws);
    u16* kvb    = (u16*)(ws + (16u << 20));
    u16* Wt     = (u16*)(ws + (32u << 20));
    u16* qh_b   = (u16*)(ws + (40u << 20));
    u16* kh_b   = (u16*)(ws + (56u << 20));
    u16* vt_b   = (u16*)(ws + (72u << 20));
    u16* attn_b = (u16*)(ws + (88u << 20));

    // 1. cast activations to bf16
    acast_kernel<<<dim3(MM * DD / (256 * 4), 2), 256, 0, stream>>>(q, kv, qb, kvb);
    // 2. transpose+cast the four weight matrices
    wt_kernel<<<dim3(16, 16, 4), 256, 0, stream>>>(Wq, Wk, Wv, Wo, Wt);
    // 3. fused QKV projection (256^2 tile, BK=64 pipeline)
    qkv_gemm<<<dim3(NN / 256, MM / 256, 3), 512, 0, stream>>>(
        qb, kvb, Wt, bq, bk, bv, qpos, kpos, q_scale, k_scale, qh_b, kh_b, vt_b);
    // 4. causal MFMA flash attention, paired complementary Q-tiles -> (B,T,N) bf16
    attn_mfma<<<dim3(TT / 128, HH, BB), 256, 0, stream>>>(qh_b, kh_b, vt_b, head_scale, attn_b);
    // 5. output projection (256^2 tile, BK=64 pipeline) + bias -> fp32
    out_gemm<<<dim3(NN / 256, MM / 256), 512, 0, stream>>>(attn_b, Wt + (size_t)3 * KK * NN, bo, out);
}

// Round 10
// 474.222 us; speedup vs baseline: 1.0554x; 1.0554x over previous
//
#include <hip/hip_runtime.h>
#include <math.h>

// Problem constants
#define BB 4
#define TT 2048
#define DD 1024
#define HH 16
#define QKD 64
#define MM (BB*TT)          // 8192
#define NN 1024             // H*QK == D
#define KK 1024

// 256x256 GEMM tile geometry
#define BKG 64              // K-step (64 MFMA/wave per barrier-pair)
#define NTSG (KK/BKG)       // 16 k-steps

typedef unsigned short u16;
typedef __attribute__((ext_vector_type(8))) short short8;   // 8 bf16 = 4 VGPRs
typedef __attribute__((ext_vector_type(4))) float float4v;  // MFMA C/D

// fp32 -> bf16 round-to-nearest-even
__device__ __forceinline__ u16 f2bf(float f) {
    union { float f; unsigned u; } v; v.f = f;
    unsigned r = (v.u + 0x7FFFu + ((v.u >> 16) & 1u)) >> 16;
    return (u16)r;
}

// packed fp32x2 -> bf16x2 (RTNE), single instruction on gfx950
__device__ __forceinline__ unsigned cvt_pk_bf16(float lo, float hi) {
    unsigned r;
    asm("v_cvt_pk_bf16_f32 %0, %1, %2" : "=v"(r) : "v"(lo), "v"(hi));
    return r;
}

// async global->LDS, 16B per lane; LDS dest = wave-uniform base + lane*16
typedef __attribute__((address_space(3))) unsigned lds_u32_t;
typedef __attribute__((address_space(1))) const unsigned glb_u32_t;
__device__ __forceinline__ void gl2lds16(const u16* g, u16* l) {
    __builtin_amdgcn_global_load_lds((glb_u32_t*)g, (lds_u32_t*)l, 16, 0, 0);
}

// Conflict-free slot swizzle for 8-slot (128B) rows read as ds_read_b128:
// slot' = slot ^ (row & 7).  This is the SAME pattern the attention kernel's
// 128B-row K/V tiles use, which measures ~0 SQ_LDS_BANK_CONFLICT.  Over 16
// consecutive rows (one lg-group), row&7 cycles 0..7 twice -> 2 rows per 16B
// granule per lg-group, uniform 8 lanes/granule across the wave = min-cycle
// service.  [Round-9's g(r)=f((r>>2)&3) was WRONG: only 2 values per 8 rows
// -> 4-way granule aliasing -> 14.4M conflict cycles measured.]
__device__ __forceinline__ int swz_slot(int row, int slot) {
    return slot ^ (row & 7);
}

// ---------------------------------------------------------------------------
// fp32 -> bf16 cast for activations (q, kv)
// ---------------------------------------------------------------------------
__global__ __launch_bounds__(256) void acast_kernel(
    const float* __restrict__ a, const float* __restrict__ b,
    u16* __restrict__ da, u16* __restrict__ db)
{
    const float* s = blockIdx.y ? b : a;
    u16* d = blockIdx.y ? db : da;
    size_t i = ((size_t)blockIdx.x * 256 + threadIdx.x) * 4;
    float4 v = *(const float4*)&s[i];
    ushort4 o = { f2bf(v.x), f2bf(v.y), f2bf(v.z), f2bf(v.w) };
    *(ushort4*)&d[i] = o;
}

// ---------------------------------------------------------------------------
// Weight transpose + cast: W[K][N] fp32 -> Wt[N][K] bf16, z selects matrix
// ---------------------------------------------------------------------------
__global__ __launch_bounds__(256) void wt_kernel(
    const float* __restrict__ Wq, const float* __restrict__ Wk,
    const float* __restrict__ Wv, const float* __restrict__ Wo,
    u16* __restrict__ dstbase)
{
    const int z = blockIdx.z;
    const float* src = (z == 0) ? Wq : (z == 1) ? Wk : (z == 2) ? Wv : Wo;
    u16* out = dstbase + (size_t)z * (KK * NN);
    const int bi = blockIdx.y, bj = blockIdx.x;  // 64x64 tile: k-block, n-block
    __shared__ float tile[64][65];
    const int t = threadIdx.x;
    #pragma unroll
    for (int p = 0; p < 4; p++) {
        int idx = p * 256 + t;
        int r = idx >> 4, c4 = (idx & 15) << 2;
        float4 v = *(const float4*)&src[(size_t)(bi * 64 + r) * NN + bj * 64 + c4];
        tile[r][c4 + 0] = v.x; tile[r][c4 + 1] = v.y;
        tile[r][c4 + 2] = v.z; tile[r][c4 + 3] = v.w;
    }
    __syncthreads();
    #pragma unroll
    for (int p = 0; p < 4; p++) {
        int idx = p * 256 + t;
        int rn = idx >> 4, c4 = (idx & 15) << 2;
        ushort4 o = { f2bf(tile[c4 + 0][rn]), f2bf(tile[c4 + 1][rn]),
                      f2bf(tile[c4 + 2][rn]), f2bf(tile[c4 + 3][rn]) };
        *(ushort4*)&out[(size_t)(bj * 64 + rn) * KK + bi * 64 + c4] = o;
    }
}

// ---------------------------------------------------------------------------
// 256x256 bf16 MFMA GEMM mainloop: BK=64 per step (64 MFMA/wave per
// barrier-pair, 16 steps), double-buffered 128KB LDS.  8 waves (512 thr),
// wave grid 2(m)x4(n), per-wave output 128x64 = acc[8][4].  gl_lds staging
// with pre-swizzled global source (swz_slot), linear LDS dest.
// Pipeline: issue tile t+1 (8 loads/thread) at START of step t -> one full
// step of latency cover; counted vmcnt(8) (drain-0 only at tail).
// A: [M,K] bf16 row-major.  Bt: [N,K] bf16 row-major (i.e. W^T).
// sh: 128KB u16[65536]: buf b at sh + b*32768 (A 16384 u16, then B 16384).
// ---------------------------------------------------------------------------
__device__ __forceinline__ void gemm256_mainloop(
    const u16* __restrict__ A, const u16* __restrict__ Bt,
    int m0, int n0, u16* __restrict__ sh, float4v (&acc)[8][4])
{
    const int tid = threadIdx.x;          // 0..511
    const int lane = tid & 63;
    const int l15 = lane & 15, lg = lane >> 4;
    const int wave = tid >> 6;
    const int wm = wave >> 2, wn = wave & 3;

    // staging: per matrix 2048 16B-chunks (256 rows x 8 slots); this thread
    // handles chunks tid + i*512 (i=0..3) for A and for B.
    const u16* gA[4]; const u16* gB[4]; int ld_off[4];
    #pragma unroll
    for (int i = 0; i < 4; i++) {
        const int c = tid + i * 512;
        const int r = c >> 3, sp = c & 7;
        const int gs = swz_slot(r, sp);          // pre-swizzled global colblock
        gA[i] = A  + (size_t)(m0 + r) * KK + gs * 8;
        gB[i] = Bt + (size_t)(n0 + r) * KK + gs * 8;
        ld_off[i] = c * 8;                       // linear LDS dest (u16 units)
    }

    auto issue = [&](int buf, int k0) {          // 8 gl_lds per thread
        u16* dA = sh + buf * 32768;
        u16* dB = dA + 16384;
        #pragma unroll
        for (int i = 0; i < 4; i++) gl2lds16(gA[i] + k0, dA + ld_off[i]);
        #pragma unroll
        for (int i = 0; i < 4; i++) gl2lds16(gB[i] + k0, dB + ld_off[i]);
    };

    issue(0, 0);                                 // tile 0 -> buf0

    for (int t = 0; t < NTSG; t++) {
        const int buf = t & 1;
        if (t + 1 < NTSG) {
            issue(buf ^ 1, (t + 1) * BKG);       // prefetch next tile
            asm volatile("s_waitcnt vmcnt(8)" ::: "memory");   // tile t landed
        } else {
            asm volatile("s_waitcnt vmcnt(0)" ::: "memory");   // tail drain
        }
        __builtin_amdgcn_s_barrier();            // tile t visible to ALL waves
        __builtin_amdgcn_sched_barrier(0);

        const u16* cA = sh + buf * 32768;
        const u16* cB = cA + 16384;

        #pragma unroll
        for (int kk = 0; kk < 2; kk++) {
            short8 af[8], bf[4];
            #pragma unroll
            for (int x = 0; x < 8; x++) {
                const int ra = wm * 128 + x * 16 + l15;
                af[x] = *(const short8*)(cA + ra * 64 + swz_slot(ra, kk * 4 + lg) * 8);
            }
            #pragma unroll
            for (int x = 0; x < 4; x++) {
                const int rb = wn * 64 + x * 16 + l15;
                bf[x] = *(const short8*)(cB + rb * 64 + swz_slot(rb, kk * 4 + lg) * 8);
            }
            __builtin_amdgcn_s_setprio(1);
            #pragma unroll
            for (int mi = 0; mi < 8; mi++)
                #pragma unroll
                for (int nj = 0; nj < 4; nj++)
                    acc[mi][nj] = __builtin_amdgcn_mfma_f32_16x16x32_bf16(af[mi], bf[nj], acc[mi][nj], 0, 0, 0);
            __builtin_amdgcn_s_setprio(0);
        }

        __builtin_amdgcn_s_barrier();   // close reads of buf before t+2 issue
        __builtin_amdgcn_sched_barrier(0);
    }
}

// XCD band swizzle for a 4(n) x 32(m) grid: flat -> (m_idx, n_idx) so each
// XCD owns a contiguous band of 4 m-rows x all 4 n-tiles (A 2MB + B 2MB fits
// the 4MB per-XCD L2).  Bijective (128 = 8 x 16).
__device__ __forceinline__ void xcd_swizzle_4x32(int& m_idx, int& n_idx) {
    const int flat = blockIdx.y * 4 + blockIdx.x;   // 0..127
    const int xcd = flat & 7, q = flat >> 3;        // q: 0..15
    m_idx = xcd * 4 + (q & 3);                      // 0..31
    n_idx = q >> 2;                                 // 0..3
}

// ---------------------------------------------------------------------------
// QKV projection GEMM (256^2 tile), z in {0:Q, 1:K, 2:V}.
// Q,K: bias + RMSNorm + RoPE -> (B,H,T,QK) bf16 (Q also * 0.125*log2e).
// V:   bias -> transposed (B,H,QK,T) bf16.
// Epilogue stores route through the (now free) LDS in two 128-row passes so
// every global store instruction writes full 128B lines.
// ---------------------------------------------------------------------------
__global__ __launch_bounds__(512, 2) void qkv_gemm(
    const u16* __restrict__ qb, const u16* __restrict__ kvb,
    const u16* __restrict__ Wt,
    const float* __restrict__ bq, const float* __restrict__ bk, const float* __restrict__ bv,
    const int* __restrict__ qpos, const int* __restrict__ kpos,
    const float* __restrict__ q_scale, const float* __restrict__ k_scale,
    u16* __restrict__ qh, u16* __restrict__ kh, u16* __restrict__ vt)
{
    __shared__ __align__(16) u16 sh[65536];   // 128 KB: 2-buf staging, then epilogue stash

    const int z = blockIdx.z;
    const u16* A        = (z == 0) ? qb : kvb;
    const u16* B        = Wt + (size_t)z * (KK * NN);
    const float* bias   = (z == 0) ? bq : (z == 1) ? bk : bv;
    const float* scl    = (z == 0) ? q_scale : k_scale;
    const int* pos_arr  = (z == 0) ? qpos : kpos;
    u16* dst            = (z == 0) ? qh : (z == 1) ? kh : vt;

    int m_idx, n_idx;
    xcd_swizzle_4x32(m_idx, n_idx);
    const int m0 = m_idx * 256, n0 = n_idx * 256;

    float4v acc[8][4];
    #pragma unroll
    for (int i = 0; i < 8; i++)
        #pragma unroll
        for (int j = 0; j < 4; j++) acc[i][j] = (float4v){0.f, 0.f, 0.f, 0.f};

    gemm256_mainloop(A, B, m0, n0, sh, acc);

    const int tid = threadIdx.x;
    const int lane = tid & 63, wave = tid >> 6;
    const int l15 = lane & 15, lg = lane >> 4;
    const int wm = wave >> 2, wn = wave & 3;

    float bia[4], sc[4];
    #pragma unroll
    for (int nj = 0; nj < 4; nj++) {
        bia[nj] = bias[n0 + wn * 64 + nj * 16 + l15];
        sc[nj]  = 1.0f + scl[nj * 16 + l15];
    }
    float invts[2];
    #pragma unroll
    for (int p = 0; p < 2; p++)
        invts[p] = powf(10000.0f, -(float)(p * 16 + l15) * (1.0f / 32.0f));

    const float QMUL = 0.125f * 1.44269504088896340736f;
    const int bb_ = m0 >> 11;       // batch (tile never straddles a batch)
    const int t0g = m0 & 2047;      // global t base of this tile

    if (z < 2) {
        // ---- Q/K epilogue: two passes of 128 rows through the LDS stash ----
        #pragma unroll
        for (int p = 0; p < 2; p++) {
            __syncthreads();
            if (wm == p) {
                #pragma unroll
                for (int mi = 0; mi < 8; mi++) {
                    #pragma unroll
                    for (int r = 0; r < 4; r++) {
                        const int tl = mi * 16 + lg * 4 + r;      // 0..127
                        const int m = m0 + p * 128 + tl;
                        const int b = m >> 11, t = m & 2047;
                        float v[4];
                        #pragma unroll
                        for (int nj = 0; nj < 4; nj++) v[nj] = acc[mi][nj][r] + bia[nj];

                        float ss = v[0]*v[0] + v[1]*v[1] + v[2]*v[2] + v[3]*v[3];
                        ss += __shfl_xor(ss, 1);
                        ss += __shfl_xor(ss, 2);
                        ss += __shfl_xor(ss, 4);
                        ss += __shfl_xor(ss, 8);
                        float rn = rsqrtf(ss * (1.0f / 64.0f) + 1e-6f);
                        #pragma unroll
                        for (int nj = 0; nj < 4; nj++) v[nj] = v[nj] * rn * sc[nj];

                        const float pos = (float)pos_arr[b * TT + t];
                        #pragma unroll
                        for (int pp = 0; pp < 2; pp++) {
                            float ang = pos * invts[pp];
                            float s = sinf(ang), c = cosf(ang);
                            float x1 = v[pp], x2 = v[pp + 2];
                            v[pp]     = x1 * c - x2 * s;
                            v[pp + 2] = x2 * c + x1 * s;
                        }
                        if (z == 0) {
                            #pragma unroll
                            for (int nj = 0; nj < 4; nj++) v[nj] *= QMUL;
                        }
                        #pragma unroll
                        for (int nj = 0; nj < 4; nj++) {
                            const int dl = wn * 64 + nj * 16 + l15;   // 0..255
                            sh[tl * 256 + (dl ^ ((tl & 7) << 3))] = f2bf(v[nj]);
                        }
                    }
                }
            }
            __syncthreads();
            // cooperative coalesced store of rows p*128..p*128+127
            #pragma unroll
            for (int it = 0; it < 8; it++) {
                int idx = it * 512 + tid;       // 0..4095
                int tl  = idx >> 5;             // 0..127
                int c8  = (idx & 31) << 3;      // 0..248 step 8
                short8 v8 = *(const short8*)&sh[tl * 256 + (c8 ^ ((tl & 7) << 3))];
                int cg = n0 + c8;
                int hh_ = cg >> 6, dih = cg & 63;
                int t = t0g + p * 128 + tl;
                *(short8*)&dst[((size_t)(bb_ * HH + hh_) * TT + t) * QKD + dih] = v8;
            }
        }
    } else {
        // ---- V epilogue: transposed stash [256 d][128 t] per pass ----
        #pragma unroll
        for (int p = 0; p < 2; p++) {
            __syncthreads();
            if (wm == p) {
                #pragma unroll
                for (int mi = 0; mi < 8; mi++) {
                    #pragma unroll
                    for (int r = 0; r < 4; r++) {
                        const int tl = mi * 16 + lg * 4 + r;      // 0..127
                        #pragma unroll
                        for (int nj = 0; nj < 4; nj++) {
                            const int dl = wn * 64 + nj * 16 + l15;   // 0..255
                            sh[dl * 128 + (tl ^ ((dl & 7) << 3))] = f2bf(acc[mi][nj][r] + bia[nj]);
                        }
                    }
                }
            }
            __syncthreads();
            #pragma unroll
            for (int it = 0; it < 8; it++) {
                int idx = it * 512 + tid;       // 0..4095
                int dl  = idx >> 4;             // 0..255
                int tc  = (idx & 15) << 3;      // 0..120 step 8
                short8 v8 = *(const short8*)&sh[dl * 128 + (tc ^ ((dl & 7) << 3))];
                int dg = n0 + dl;
                int hh_ = dg >> 6, dih = dg & 63;
                *(short8*)&vt[((size_t)(bb_ * HH + hh_) * QKD + dih) * TT + t0g + p * 128 + tc] = v8;
            }
        }
    }
}

// ---------------------------------------------------------------------------
// Output projection GEMM (256^2): attn_b[M,K] bf16 @ Wo_t[N,K]^T + bo -> fp32
// ---------------------------------------------------------------------------
__global__ __launch_bounds__(512, 2) void out_gemm(
    const u16* __restrict__ A, const u16* __restrict__ Bt,
    const float* __restrict__ bo, float* __restrict__ out)
{
    __shared__ __align__(16) u16 sh[65536];

    int m_idx, n_idx;
    xcd_swizzle_4x32(m_idx, n_idx);
    const int m0 = m_idx * 256, n0 = n_idx * 256;

    float4v acc[8][4];
    #pragma unroll
    for (int i = 0; i < 8; i++)
        #pragma unroll
        for (int j = 0; j < 4; j++) acc[i][j] = (float4v){0.f, 0.f, 0.f, 0.f};

    gemm256_mainloop(A, Bt, m0, n0, sh, acc);

    const int lane = threadIdx.x & 63, wave = threadIdx.x >> 6;
    const int l15 = lane & 15, lg = lane >> 4;
    const int wm = wave >> 2, wn = wave & 3;

    float bov[4];
    #pragma unroll
    for (int nj = 0; nj < 4; nj++) bov[nj] = bo[n0 + wn * 64 + nj * 16 + l15];

    #pragma unroll
    for (int mi = 0; mi < 8; mi++)
        #pragma unroll
        for (int r = 0; r < 4; r++) {
            const int m = m0 + wm * 128 + mi * 16 + lg * 4 + r;
            float* op = out + (size_t)m * NN + n0 + wn * 64 + l15;
            #pragma unroll
            for (int nj = 0; nj < 4; nj++)
                op[nj * 16] = acc[mi][nj][r] + bov[nj];
        }
}

// ---------------------------------------------------------------------------
// MFMA flash attention, causal.  PAIRED COMPLEMENTARY Q-TILES (unchanged).
// Block p processes qt_a = p and qt_b = 31-p: per-block work = 33 row-tiles
// (uniform), grid = 16x16x4 = 1024 blocks = exactly 4/CU.  K/V tile jt is
// staged ONCE and consumed by both Q-tiles (qt_b always, qt_a while jt <= p).
// ---------------------------------------------------------------------------
__global__ __launch_bounds__(256) void attn_mfma(
    const u16* __restrict__ qh, const u16* __restrict__ kh,
    const u16* __restrict__ vt, const float* __restrict__ head_scale,
    u16* __restrict__ out)
{
    __shared__ __align__(16) u16 Ks[2][64 * 64];   // K rows (swizzled)
    __shared__ __align__(16) u16 Vs[2][64 * 64];   // V^T rows = d (swizzled)
    __shared__ __align__(16) u16 Ps[4][16 * 64];   // per-wave P tile (swizzled)

    const int b = blockIdx.z, h = blockIdx.y;
    const int qta = blockIdx.x;          // 0..15  (small tile)
    const int qtb = 31 - qta;            // 16..31 (big tile)
    const int t0a = qta * 64, t0b = qtb * 64;

    const int tid  = threadIdx.x;
    const int wave = tid >> 6, lane = tid & 63;
    const int l15 = lane & 15, lg = lane >> 4;
    const int l7 = l15 & 7;

    const size_t bh = (size_t)(b * HH + h);
    const u16* qbh  = qh + bh * TT * QKD;
    const u16* kbh  = kh + bh * TT * QKD;
    const u16* vtbh = vt + bh * QKD * TT;   // [QKD][TT]

    short8 qfA[2], qfB[2];
    #pragma unroll
    for (int kc = 0; kc < 2; kc++) {
        qfA[kc] = *(const short8*)(qbh + (size_t)(t0a + wave * 16 + l15) * QKD
                                    + kc * 32 + lg * 8);
        qfB[kc] = *(const short8*)(qbh + (size_t)(t0b + wave * 16 + l15) * QKD
                                    + kc * 32 + lg * 8);
    }

    auto stage = [&](int buf, int j0s) {
        #pragma unroll
        for (int rr = 0; rr < 2; rr++) {
            const int c   = rr * 256 + tid;     // chunk 0..511 (16B each)
            const int row = c >> 3;             // 0..63
            const int g   = (c & 7) ^ (row & 7);// pre-swizzled global colblock
            u16* ldsK = &Ks[buf][(rr * 256 + (wave << 6)) * 8];
            u16* ldsV = &Vs[buf][(rr * 256 + (wave << 6)) * 8];
            gl2lds16(kbh  + (size_t)(j0s + row) * QKD + g * 8, ldsK);
            gl2lds16(vtbh + (size_t)row * TT + j0s + g * 8, ldsV);
        }
    };

    float4v oA[4], oB[4];
    #pragma unroll
    for (int nt = 0; nt < 4; nt++) {
        oA[nt] = (float4v){0.f, 0.f, 0.f, 0.f};
        oB[nt] = (float4v){0.f, 0.f, 0.f, 0.f};
    }
    float mA[4] = {-INFINITY, -INFINITY, -INFINITY, -INFINITY};
    float mB[4] = {-INFINITY, -INFINITY, -INFINITY, -INFINITY};
    float lA[4] = {0.f, 0.f, 0.f, 0.f};
    float lB[4] = {0.f, 0.f, 0.f, 0.f};

    auto flash_step = [&](int cur, int jt, int qt_self,
                          short8 (&qf)[2], float4v (&oa)[4],
                          float (&mr)[4], float (&lr)[4]) {
        // ---- QK^T (swizzled K reads) ----
        float4v sarr[4];
        #pragma unroll
        for (int nt = 0; nt < 4; nt++) {
            float4v s = (float4v){0.f, 0.f, 0.f, 0.f};
            #pragma unroll
            for (int kc = 0; kc < 2; kc++) {
                const short8 bfrag = *(const short8*)
                    &Ks[cur][(nt * 16 + l15) * 64 + ((kc * 4 + lg) ^ l7) * 8];
                s = __builtin_amdgcn_mfma_f32_16x16x32_bf16(qf[kc], bfrag, s, 0, 0, 0);
            }
            sarr[nt] = s;
        }

        // ---- causal mask (diagonal tile only) ----
        if (jt == qt_self) {
            const int qbase = qt_self * 64 + wave * 16 + lg * 4;
            #pragma unroll
            for (int nt = 0; nt < 4; nt++) {
                int jkey = jt * 64 + nt * 16 + l15;
                #pragma unroll
                for (int r = 0; r < 4; r++)
                    if (jkey > qbase + r) sarr[nt][r] = -INFINITY;
            }
        }

        // ---- row max + defer-max rescale (T13) ----
        float pm[4];
        #pragma unroll
        for (int r = 0; r < 4; r++) {
            float m = fmaxf(fmaxf(sarr[0][r], sarr[1][r]), fmaxf(sarr[2][r], sarr[3][r]));
            m = fmaxf(m, __shfl_xor(m, 1));
            m = fmaxf(m, __shfl_xor(m, 2));
            m = fmaxf(m, __shfl_xor(m, 4));
            m = fmaxf(m, __shfl_xor(m, 8));
            pm[r] = m;
        }
        float grow = fmaxf(fmaxf(pm[0] - mr[0], pm[1] - mr[1]),
                           fmaxf(pm[2] - mr[2], pm[3] - mr[3]));
        if (__any(grow > 8.0f)) {
            #pragma unroll
            for (int r = 0; r < 4; r++) {
                float mn = fmaxf(mr[r], pm[r]);
                float a  = exp2f(mr[r] - mn);
                mr[r] = mn;
                lr[r] *= a;
                #pragma unroll
                for (int nt = 0; nt < 4; nt++) oa[nt][r] *= a;
            }
        }

        // ---- P = exp2(S - m), partial rowsum, packed bf16 store to Ps ----
        u16* pw = Ps[wave];
        float lp[4] = {0.f, 0.f, 0.f, 0.f};
        #pragma unroll
        for (int nt = 0; nt < 4; nt++) {
            float p0 = exp2f(sarr[nt][0] - mr[0]);
            float p1 = exp2f(sarr[nt][1] - mr[1]);
            float p2 = exp2f(sarr[nt][2] - mr[2]);
            float p3 = exp2f(sarr[nt][3] - mr[3]);
            lp[0] += p0; lp[1] += p1; lp[2] += p2; lp[3] += p3;
            unsigned wlo = cvt_pk_bf16(p0, p1);
            unsigned whi = cvt_pk_bf16(p2, p3);
            const int gb = nt * 2 + (l15 >> 3);
            const int r0 = lg * 4;
            pw[(r0 + 0) * 64 + ((gb ^ ((r0 + 0) & 7))) * 8 + l7] = (u16)wlo;
            pw[(r0 + 1) * 64 + ((gb ^ ((r0 + 1) & 7))) * 8 + l7] = (u16)(wlo >> 16);
            pw[(r0 + 2) * 64 + ((gb ^ ((r0 + 2) & 7))) * 8 + l7] = (u16)whi;
            pw[(r0 + 3) * 64 + ((gb ^ ((r0 + 3) & 7))) * 8 + l7] = (u16)(whi >> 16);
        }
        #pragma unroll
        for (int r = 0; r < 4; r++) lr[r] += lp[r];

        // ---- read P fragments back (same wave; lgkmcnt ordered) ----
        short8 pf[2];
        #pragma unroll
        for (int kc = 0; kc < 2; kc++)
            pf[kc] = *(const short8*)&pw[l15 * 64 + ((kc * 4 + lg) ^ l7) * 8];

        // ---- PV (swizzled V^T reads) ----
        #pragma unroll
        for (int nt = 0; nt < 4; nt++) {
            #pragma unroll
            for (int kc = 0; kc < 2; kc++) {
                const short8 vfrag = *(const short8*)
                    &Vs[cur][(nt * 16 + l15) * 64 + ((kc * 4 + lg) ^ l7) * 8];
                oa[nt] = __builtin_amdgcn_mfma_f32_16x16x32_bf16(pf[kc], vfrag, oa[nt], 0, 0, 0);
            }
        }
    };

    stage(0, 0);
    __syncthreads();

    const int njt = qtb + 1;     // jt = 0..qtb
    for (int jt = 0; jt < njt; jt++) {
        const int cur = jt & 1;
        if (jt + 1 < njt) stage(cur ^ 1, (jt + 1) * 64);   // prefetch next tile

        flash_step(cur, jt, qtb, qfB, oB, mB, lB);          // big tile: always
        if (jt <= qta)
            flash_step(cur, jt, qta, qfA, oA, mA, lA);      // small tile: prefix

        __syncthreads();   // drains prefetch vmcnt + protects buffer reuse
    }

    // ---- epilogue: both Q-tiles ----
    const float hs = 1.0f + head_scale[h];
    auto epilogue = [&](int t0, float4v (&oa)[4], float (&lr)[4]) {
        #pragma unroll
        for (int r = 0; r < 4; r++) {
            float l = lr[r];
            l += __shfl_xor(l, 1);
            l += __shfl_xor(l, 2);
            l += __shfl_xor(l, 4);
            l += __shfl_xor(l, 8);
            const int q = t0 + wave * 16 + lg * 4 + r;
            const float f = hs / l;
            u16* op = out + ((size_t)(b * TT + q) * NN) + h * QKD + l15;
            #pragma unroll
            for (int nt = 0; nt < 4; nt++)
                op[nt * 16] = f2bf(oa[nt][r] * f);
        }
    };
    epilogue(t0b, oB, lB);
    epilogue(t0a, oA, lA);
}

// ---------------------------------------------------------------------------
extern "C" void kernel_launch(void* const* d_in, const int* in_sizes, int n_in,
                              void* d_out, int out_size, void* d_ws, size_t ws_size,
                              hipStream_t stream)
{
    const float* q          = (const float*)d_in[0];
    const float* kv         = (const float*)d_in[1];
    /* d_in[2] = causal mask -- handled analytically */
    const int*   qpos       = (const int*)d_in[3];
    const int*   kpos       = (const int*)d_in[4];
    const float* Wq         = (const float*)d_in[5];
    const float* bq         = (const float*)d_in[6];
    const float* Wk         = (const float*)d_in[7];
    const float* bk         = (const float*)d_in[8];
    const float* Wv         = (const float*)d_in[9];
    const float* bv         = (const float*)d_in[10];
    const float* q_scale    = (const float*)d_in[11];
    const float* k_scale    = (const float*)d_in[12];
    const float* head_scale = (const float*)d_in[13];
    const float* Wo         = (const float*)d_in[14];
    const float* bo         = (const float*)d_in[15];
    float* out = (float*)d_out;

    // workspace layout (bytes):
    //   [  0 MB, 16 MB)  qb    (M,K) bf16
    //   [ 16 MB, 32 MB)  kvb   (M,K) bf16
    //   [ 32 MB, 40 MB)  Wt    4 x (N,K) bf16 transposed: Wq,Wk,Wv,Wo
    //   [ 40 MB, 56 MB)  qh_b  (B,H,T,QK) bf16
    //   [ 56 MB, 72 MB)  kh_b  (B,H,T,QK) bf16
    //   [ 72 MB, 88 MB)  vt_b  (B,H,QK,T) bf16  <-- V stored transposed
    //   [ 88 MB,104 MB)  attn_b (B,T,N) bf16
    char* ws = (char*)d_ws;
    u16* qb     = (u16*)(ws);
    u16* kvb    = (u16*)(ws + (16u << 20));
    u16* Wt     = (u16*)(ws + (32u << 20));
    u16* qh_b   = (u16*)(ws + (40u << 20));
    u16* kh_b   = (u16*)(ws + (56u << 20));
    u16* vt_b   = (u16*)(ws + (72u << 20));
    u16* attn_b = (u16*)(ws + (88u << 20));

    // 1. cast activations to bf16
    acast_kernel<<<dim3(MM * DD / (256 * 4), 2), 256, 0, stream>>>(q, kv, qb, kvb);
    // 2. transpose+cast the four weight matrices
    wt_kernel<<<dim3(16, 16, 4), 256, 0, stream>>>(Wq, Wk, Wv, Wo, Wt);
    // 3. fused QKV projection (256^2 tile, BK=64 pipeline, conflict-free swizzle)
    qkv_gemm<<<dim3(NN / 256, MM / 256, 3), 512, 0, stream>>>(
        qb, kvb, Wt, bq, bk, bv, qpos, kpos, q_scale, k_scale, qh_b, kh_b, vt_b);
    // 4. causal MFMA flash attention, paired complementary Q-tiles -> (B,T,N) bf16
    attn_mfma<<<dim3(TT / 128, HH, BB), 256, 0, stream>>>(qh_b, kh_b, vt_b, head_scale, attn_b);
    // 5. output projection (256^2 tile, BK=64 pipeline) + bias -> fp32
    out_gemm<<<dim3(NN / 256, MM / 256), 512, 0, stream>>>(attn_b, Wt + (size_t)3 * KK * NN, bo, out);
}

// Round 12
// 428.002 us; speedup vs baseline: 1.1694x; 1.1080x over previous
//
#include <hip/hip_runtime.h>
#include <math.h>

// Problem constants
#define BB 4
#define TT 2048
#define DD 1024
#define HH 16
#define QKD 64
#define MM (BB*TT)          // 8192
#define NN 1024             // H*QK == D
#define KK 1024

// GEMM tile geometry: BM=256 x BN=64, BK=64, 4 waves, 2 blocks/CU
#define BKG 64
#define NTSG (KK/BKG)       // 16 k-steps
#define LDSBUF 20480        // u16 per buffer: A 16384 + B 4096 (40 KB)

typedef unsigned short u16;
typedef __attribute__((ext_vector_type(8))) short short8;   // 8 bf16 = 4 VGPRs
typedef __attribute__((ext_vector_type(4))) float float4v;  // MFMA C/D

// fp32 -> bf16 round-to-nearest-even
__device__ __forceinline__ u16 f2bf(float f) {
    union { float f; unsigned u; } v; v.f = f;
    unsigned r = (v.u + 0x7FFFu + ((v.u >> 16) & 1u)) >> 16;
    return (u16)r;
}

// packed fp32x2 -> bf16x2 (RTNE), single instruction on gfx950
__device__ __forceinline__ unsigned cvt_pk_bf16(float lo, float hi) {
    unsigned r;
    asm("v_cvt_pk_bf16_f32 %0, %1, %2" : "=v"(r) : "v"(lo), "v"(hi));
    return r;
}

// async global->LDS, 16B per lane; LDS dest = wave-uniform base + lane*16
typedef __attribute__((address_space(3))) unsigned lds_u32_t;
typedef __attribute__((address_space(1))) const unsigned glb_u32_t;
__device__ __forceinline__ void gl2lds16(const u16* g, u16* l) {
    __builtin_amdgcn_global_load_lds((glb_u32_t*)g, (lds_u32_t*)l, 16, 0, 0);
}

// Conflict-free slot swizzle for 8-slot (128B) rows read as ds_read_b128:
// slot' = slot ^ (row & 7).  Verified on HW: 262K conflict cycles (vs 14.4M
// for the broken r9 variant) -- same pattern as the attn K/V tiles.
__device__ __forceinline__ int swz_slot(int row, int slot) {
    return slot ^ (row & 7);
}

// ---------------------------------------------------------------------------
// fp32 -> bf16 cast for activations (q, kv)
// ---------------------------------------------------------------------------
__global__ __launch_bounds__(256) void acast_kernel(
    const float* __restrict__ a, const float* __restrict__ b,
    u16* __restrict__ da, u16* __restrict__ db)
{
    const float* s = blockIdx.y ? b : a;
    u16* d = blockIdx.y ? db : da;
    size_t i = ((size_t)blockIdx.x * 256 + threadIdx.x) * 4;
    float4 v = *(const float4*)&s[i];
    ushort4 o = { f2bf(v.x), f2bf(v.y), f2bf(v.z), f2bf(v.w) };
    *(ushort4*)&d[i] = o;
}

// ---------------------------------------------------------------------------
// Weight transpose + cast: W[K][N] fp32 -> Wt[N][K] bf16, z selects matrix
// ---------------------------------------------------------------------------
__global__ __launch_bounds__(256) void wt_kernel(
    const float* __restrict__ Wq, const float* __restrict__ Wk,
    const float* __restrict__ Wv, const float* __restrict__ Wo,
    u16* __restrict__ dstbase)
{
    const int z = blockIdx.z;
    const float* src = (z == 0) ? Wq : (z == 1) ? Wk : (z == 2) ? Wv : Wo;
    u16* out = dstbase + (size_t)z * (KK * NN);
    const int bi = blockIdx.y, bj = blockIdx.x;  // 64x64 tile: k-block, n-block
    __shared__ float tile[64][65];
    const int t = threadIdx.x;
    #pragma unroll
    for (int p = 0; p < 4; p++) {
        int idx = p * 256 + t;
        int r = idx >> 4, c4 = (idx & 15) << 2;
        float4 v = *(const float4*)&src[(size_t)(bi * 64 + r) * NN + bj * 64 + c4];
        tile[r][c4 + 0] = v.x; tile[r][c4 + 1] = v.y;
        tile[r][c4 + 2] = v.z; tile[r][c4 + 3] = v.w;
    }
    __syncthreads();
    #pragma unroll
    for (int p = 0; p < 4; p++) {
        int idx = p * 256 + t;
        int rn = idx >> 4, c4 = (idx & 15) << 2;
        ushort4 o = { f2bf(tile[c4 + 0][rn]), f2bf(tile[c4 + 1][rn]),
                      f2bf(tile[c4 + 2][rn]), f2bf(tile[c4 + 3][rn]) };
        *(ushort4*)&out[(size_t)(bj * 64 + rn) * KK + bi * 64 + c4] = o;
    }
}

// ---------------------------------------------------------------------------
// 256x64 bf16 MFMA GEMM mainloop: BK=64 per step (16 steps), double-buffered
// 80KB LDS -> 2 BLOCKS/CU co-resident (m114 implicit cross-block overlap:
// while one block parks at its barrier, the other issues MFMA).  4 waves
// (256 thr); wave w owns output rows [w*64, w*64+64) x all 64 cols =
// acc[4][4].  gl_lds staging, pre-swizzled global source (swz_slot), linear
// LDS dest.  Prefetch tile t+1 at step start; counted vmcnt(10) (10 loads
// per issue), drain-0 only at tail.
// A: [M,K] bf16 row-major.  Bt: [N,K] bf16 row-major (i.e. W^T).
// sh: u16[2*LDSBUF]: buf b at sh + b*LDSBUF (A 16384 u16, then B 4096 u16).
// ---------------------------------------------------------------------------
__device__ __forceinline__ void gemm_mainloop_256x64(
    const u16* __restrict__ A, const u16* __restrict__ Bt,
    int m0, int n0, u16* __restrict__ sh, float4v (&acc)[4][4])
{
    const int tid = threadIdx.x;          // 0..255
    const int lane = tid & 63;
    const int l15 = lane & 15, lg = lane >> 4;
    const int wave = tid >> 6;            // 0..3 = m-quadrant

    // staging: A = 2048 chunks (256 rows x 8 slots) -> 8/thread;
    //          B =  512 chunks ( 64 rows x 8 slots) -> 2/thread.
    const u16* gA[8]; int offA[8];
    #pragma unroll
    for (int i = 0; i < 8; i++) {
        const int c = tid + i * 256;
        const int r = c >> 3, sp = c & 7;
        gA[i] = A + (size_t)(m0 + r) * KK + swz_slot(r, sp) * 8;
        offA[i] = c * 8;
    }
    const u16* gB[2]; int offB[2];
    #pragma unroll
    for (int i = 0; i < 2; i++) {
        const int c = tid + i * 256;
        const int r = c >> 3, sp = c & 7;
        gB[i] = Bt + (size_t)(n0 + r) * KK + swz_slot(r, sp) * 8;
        offB[i] = c * 8;
    }

    auto issue = [&](int buf, int k0) {          // 10 gl_lds per thread
        u16* dA = sh + buf * LDSBUF;
        u16* dB = dA + 16384;
        #pragma unroll
        for (int i = 0; i < 8; i++) gl2lds16(gA[i] + k0, dA + offA[i]);
        #pragma unroll
        for (int i = 0; i < 2; i++) gl2lds16(gB[i] + k0, dB + offB[i]);
    };

    issue(0, 0);                                 // tile 0 -> buf0

    for (int t = 0; t < NTSG; t++) {
        const int buf = t & 1;
        if (t + 1 < NTSG) {
            issue(buf ^ 1, (t + 1) * BKG);       // prefetch next tile
            asm volatile("s_waitcnt vmcnt(10)" ::: "memory");  // tile t landed
        } else {
            asm volatile("s_waitcnt vmcnt(0)" ::: "memory");   // tail drain
        }
        __builtin_amdgcn_s_barrier();            // tile t visible to ALL waves
        __builtin_amdgcn_sched_barrier(0);

        const u16* cA = sh + buf * LDSBUF;
        const u16* cB = cA + 16384;

        #pragma unroll
        for (int kk = 0; kk < 2; kk++) {
            short8 af[4], bf[4];
            #pragma unroll
            for (int x = 0; x < 4; x++) {
                const int ra = wave * 64 + x * 16 + l15;
                af[x] = *(const short8*)(cA + ra * 64 + swz_slot(ra, kk * 4 + lg) * 8);
            }
            #pragma unroll
            for (int x = 0; x < 4; x++) {
                const int rb = x * 16 + l15;
                bf[x] = *(const short8*)(cB + rb * 64 + swz_slot(rb, kk * 4 + lg) * 8);
            }
            __builtin_amdgcn_s_setprio(1);
            #pragma unroll
            for (int mi = 0; mi < 4; mi++)
                #pragma unroll
                for (int nj = 0; nj < 4; nj++)
                    acc[mi][nj] = __builtin_amdgcn_mfma_f32_16x16x32_bf16(af[mi], bf[nj], acc[mi][nj], 0, 0, 0);
            __builtin_amdgcn_s_setprio(0);
        }

        __builtin_amdgcn_s_barrier();   // close reads of buf before t+2 issue
        __builtin_amdgcn_sched_barrier(0);
    }
}

// XCD band swizzle for a 16(n) x 32(m) grid (512 blocks): each XCD owns a
// contiguous band of 4 m-rows x all 16 n-tiles.  Working set per XCD:
// 4 A-panels (2MB) + all B (2MB) = 4MB = per-XCD L2.  Bijective (512 = 8x64).
__device__ __forceinline__ void xcd_swizzle_16x32(int& m_idx, int& n_idx) {
    const int flat = blockIdx.y * 16 + blockIdx.x;  // 0..511
    const int xcd = flat & 7, q = flat >> 3;        // q: 0..63
    m_idx = xcd * 4 + (q & 3);                      // 0..31
    n_idx = q >> 2;                                 // 0..15
}

// ---------------------------------------------------------------------------
// QKV projection GEMM (256x64 tile), z in {0:Q, 1:K, 2:V}.  One head/block.
// Q,K: bias + RMSNorm + RoPE -> (B,H,T,QK) bf16 (Q also * 0.125*log2e).
// V:   bias -> transposed (B,H,QK,T) bf16.
// Epilogue routes through the freed LDS so every global store instruction
// writes full 128B lines (Q/K: linear [256t][64d] stash; V: XOR [64d][256t]).
// ---------------------------------------------------------------------------
__global__ __launch_bounds__(256, 2) void qkv_gemm(
    const u16* __restrict__ qb, const u16* __restrict__ kvb,
    const u16* __restrict__ Wt,
    const float* __restrict__ bq, const float* __restrict__ bk, const float* __restrict__ bv,
    const int* __restrict__ qpos, const int* __restrict__ kpos,
    const float* __restrict__ q_scale, const float* __restrict__ k_scale,
    u16* __restrict__ qh, u16* __restrict__ kh, u16* __restrict__ vt)
{
    __shared__ __align__(16) u16 sh[2 * LDSBUF];   // 80 KB staging, reused by epilogue

    const int z = blockIdx.z;
    const u16* A        = (z == 0) ? qb : kvb;
    const u16* B        = Wt + (size_t)z * (KK * NN);
    const float* bias   = (z == 0) ? bq : (z == 1) ? bk : bv;
    const float* scl    = (z == 0) ? q_scale : k_scale;
    const int* pos_arr  = (z == 0) ? qpos : kpos;
    u16* dst            = (z == 0) ? qh : (z == 1) ? kh : vt;

    int m_idx, n_idx;
    xcd_swizzle_16x32(m_idx, n_idx);
    const int m0 = m_idx * 256, n0 = n_idx * 64;
    const int h = n_idx;                 // one 64-col head per block

    float4v acc[4][4];
    #pragma unroll
    for (int i = 0; i < 4; i++)
        #pragma unroll
        for (int j = 0; j < 4; j++) acc[i][j] = (float4v){0.f, 0.f, 0.f, 0.f};

    gemm_mainloop_256x64(A, B, m0, n0, sh, acc);

    const int tid = threadIdx.x;
    const int lane = tid & 63, wave = tid >> 6;
    const int l15 = lane & 15, lg = lane >> 4;

    float bia[4], sc[4];
    #pragma unroll
    for (int nj = 0; nj < 4; nj++) {
        bia[nj] = bias[n0 + nj * 16 + l15];
        sc[nj]  = 1.0f + scl[nj * 16 + l15];
    }
    float invts[2];
    #pragma unroll
    for (int p = 0; p < 2; p++)
        invts[p] = powf(10000.0f, -(float)(p * 16 + l15) * (1.0f / 32.0f));

    const float QMUL = 0.125f * 1.44269504088896340736f;
    const int bb_ = m0 >> 11;       // batch (tile never straddles a batch)
    const int t0g = m0 & 2047;      // global t base of this tile

    __syncthreads();   // mainloop done; reuse sh as epilogue stash

    if (z < 2) {
        // ---- Q/K: linear stash [256 t][64 d] (32 KB) ----
        #pragma unroll
        for (int mi = 0; mi < 4; mi++) {
            #pragma unroll
            for (int r = 0; r < 4; r++) {
                const int tl = wave * 64 + mi * 16 + lg * 4 + r;   // 0..255
                const int m = m0 + tl;
                const int b = m >> 11, t = m & 2047;
                float v[4];
                #pragma unroll
                for (int nj = 0; nj < 4; nj++) v[nj] = acc[mi][nj][r] + bia[nj];

                float ss = v[0]*v[0] + v[1]*v[1] + v[2]*v[2] + v[3]*v[3];
                ss += __shfl_xor(ss, 1);
                ss += __shfl_xor(ss, 2);
                ss += __shfl_xor(ss, 4);
                ss += __shfl_xor(ss, 8);
                float rn = rsqrtf(ss * (1.0f / 64.0f) + 1e-6f);
                #pragma unroll
                for (int nj = 0; nj < 4; nj++) v[nj] = v[nj] * rn * sc[nj];

                const float pos = (float)pos_arr[b * TT + t];
                #pragma unroll
                for (int pp = 0; pp < 2; pp++) {
                    float ang = pos * invts[pp];
                    float s = sinf(ang), c = cosf(ang);
                    float x1 = v[pp], x2 = v[pp + 2];
                    v[pp]     = x1 * c - x2 * s;
                    v[pp + 2] = x2 * c + x1 * s;
                }
                if (z == 0) {
                    #pragma unroll
                    for (int nj = 0; nj < 4; nj++) v[nj] *= QMUL;
                }
                #pragma unroll
                for (int nj = 0; nj < 4; nj++)
                    sh[tl * 64 + nj * 16 + l15] = f2bf(v[nj]);
            }
        }
        __syncthreads();
        // coalesced store: 8 lanes per 128B t-row, 8 full rows per instr
        #pragma unroll
        for (int it = 0; it < 8; it++) {
            int idx = it * 256 + tid;       // 0..2047
            int tl  = idx >> 3;             // 0..255
            int c8  = (idx & 7) << 3;       // 0..56 step 8
            short8 v8 = *(const short8*)&sh[tl * 64 + c8];
            *(short8*)&dst[((size_t)(bb_ * HH + h) * TT + t0g + tl) * QKD + c8] = v8;
        }
    } else {
        // ---- V: XOR-swizzled transposed stash [64 d][256 t] (32 KB) ----
        #pragma unroll
        for (int mi = 0; mi < 4; mi++) {
            #pragma unroll
            for (int r = 0; r < 4; r++) {
                const int tl = wave * 64 + mi * 16 + lg * 4 + r;   // 0..255
                #pragma unroll
                for (int nj = 0; nj < 4; nj++) {
                    const int dl = nj * 16 + l15;                  // 0..63
                    sh[dl * 256 + (tl ^ ((dl & 7) << 3))] = f2bf(acc[mi][nj][r] + bia[nj]);
                }
            }
        }
        __syncthreads();
        #pragma unroll
        for (int it = 0; it < 8; it++) {
            int idx = it * 256 + tid;       // 0..2047
            int dl  = idx >> 5;             // 0..63
            int tc  = (idx & 31) << 3;      // 0..248 step 8
            short8 v8 = *(const short8*)&sh[dl * 256 + (tc ^ ((dl & 7) << 3))];
            *(short8*)&vt[((size_t)(bb_ * HH + h) * QKD + dl) * TT + t0g + tc] = v8;
        }
    }
}

// ---------------------------------------------------------------------------
// Output projection GEMM (256x64): attn_b[M,K] bf16 @ Wo_t[N,K]^T + bo -> fp32
// ---------------------------------------------------------------------------
__global__ __launch_bounds__(256, 2) void out_gemm(
    const u16* __restrict__ A, const u16* __restrict__ Bt,
    const float* __restrict__ bo, float* __restrict__ out)
{
    __shared__ __align__(16) u16 sh[2 * LDSBUF];

    int m_idx, n_idx;
    xcd_swizzle_16x32(m_idx, n_idx);
    const int m0 = m_idx * 256, n0 = n_idx * 64;

    float4v acc[4][4];
    #pragma unroll
    for (int i = 0; i < 4; i++)
        #pragma unroll
        for (int j = 0; j < 4; j++) acc[i][j] = (float4v){0.f, 0.f, 0.f, 0.f};

    gemm_mainloop_256x64(A, Bt, m0, n0, sh, acc);

    const int lane = threadIdx.x & 63, wave = threadIdx.x >> 6;
    const int l15 = lane & 15, lg = lane >> 4;

    float bov[4];
    #pragma unroll
    for (int nj = 0; nj < 4; nj++) bov[nj] = bo[n0 + nj * 16 + l15];

    #pragma unroll
    for (int mi = 0; mi < 4; mi++)
        #pragma unroll
        for (int r = 0; r < 4; r++) {
            const int m = m0 + wave * 64 + mi * 16 + lg * 4 + r;
            float* op = out + (size_t)m * NN + n0 + l15;
            #pragma unroll
            for (int nj = 0; nj < 4; nj++)
                op[nj * 16] = acc[mi][nj][r] + bov[nj];
        }
}

// ---------------------------------------------------------------------------
// MFMA flash attention, causal.  PAIRED COMPLEMENTARY Q-TILES (unchanged).
// Block p processes qt_a = p and qt_b = 31-p: per-block work = 33 row-tiles
// (uniform), grid = 16x16x4 = 1024 blocks = exactly 4/CU.  K/V tile jt is
// staged ONCE and consumed by both Q-tiles (qt_b always, qt_a while jt <= p).
// ---------------------------------------------------------------------------
__global__ __launch_bounds__(256) void attn_mfma(
    const u16* __restrict__ qh, const u16* __restrict__ kh,
    const u16* __restrict__ vt, const float* __restrict__ head_scale,
    u16* __restrict__ out)
{
    __shared__ __align__(16) u16 Ks[2][64 * 64];   // K rows (swizzled)
    __shared__ __align__(16) u16 Vs[2][64 * 64];   // V^T rows = d (swizzled)
    __shared__ __align__(16) u16 Ps[4][16 * 64];   // per-wave P tile (swizzled)

    const int b = blockIdx.z, h = blockIdx.y;
    const int qta = blockIdx.x;          // 0..15  (small tile)
    const int qtb = 31 - qta;            // 16..31 (big tile)
    const int t0a = qta * 64, t0b = qtb * 64;

    const int tid  = threadIdx.x;
    const int wave = tid >> 6, lane = tid & 63;
    const int l15 = lane & 15, lg = lane >> 4;
    const int l7 = l15 & 7;

    const size_t bh = (size_t)(b * HH + h);
    const u16* qbh  = qh + bh * TT * QKD;
    const u16* kbh  = kh + bh * TT * QKD;
    const u16* vtbh = vt + bh * QKD * TT;   // [QKD][TT]

    short8 qfA[2], qfB[2];
    #pragma unroll
    for (int kc = 0; kc < 2; kc++) {
        qfA[kc] = *(const short8*)(qbh + (size_t)(t0a + wave * 16 + l15) * QKD
                                    + kc * 32 + lg * 8);
        qfB[kc] = *(const short8*)(qbh + (size_t)(t0b + wave * 16 + l15) * QKD
                                    + kc * 32 + lg * 8);
    }

    auto stage = [&](int buf, int j0s) {
        #pragma unroll
        for (int rr = 0; rr < 2; rr++) {
            const int c   = rr * 256 + tid;     // chunk 0..511 (16B each)
            const int row = c >> 3;             // 0..63
            const int g   = (c & 7) ^ (row & 7);// pre-swizzled global colblock
            u16* ldsK = &Ks[buf][(rr * 256 + (wave << 6)) * 8];
            u16* ldsV = &Vs[buf][(rr * 256 + (wave << 6)) * 8];
            gl2lds16(kbh  + (size_t)(j0s + row) * QKD + g * 8, ldsK);
            gl2lds16(vtbh + (size_t)row * TT + j0s + g * 8, ldsV);
        }
    };

    float4v oA[4], oB[4];
    #pragma unroll
    for (int nt = 0; nt < 4; nt++) {
        oA[nt] = (float4v){0.f, 0.f, 0.f, 0.f};
        oB[nt] = (float4v){0.f, 0.f, 0.f, 0.f};
    }
    float mA[4] = {-INFINITY, -INFINITY, -INFINITY, -INFINITY};
    float mB[4] = {-INFINITY, -INFINITY, -INFINITY, -INFINITY};
    float lA[4] = {0.f, 0.f, 0.f, 0.f};
    float lB[4] = {0.f, 0.f, 0.f, 0.f};

    auto flash_step = [&](int cur, int jt, int qt_self,
                          short8 (&qf)[2], float4v (&oa)[4],
                          float (&mr)[4], float (&lr)[4]) {
        // ---- QK^T (swizzled K reads) ----
        float4v sarr[4];
        #pragma unroll
        for (int nt = 0; nt < 4; nt++) {
            float4v s = (float4v){0.f, 0.f, 0.f, 0.f};
            #pragma unroll
            for (int kc = 0; kc < 2; kc++) {
                const short8 bfrag = *(const short8*)
                    &Ks[cur][(nt * 16 + l15) * 64 + ((kc * 4 + lg) ^ l7) * 8];
                s = __builtin_amdgcn_mfma_f32_16x16x32_bf16(qf[kc], bfrag, s, 0, 0, 0);
            }
            sarr[nt] = s;
        }

        // ---- causal mask (diagonal tile only) ----
        if (jt == qt_self) {
            const int qbase = qt_self * 64 + wave * 16 + lg * 4;
            #pragma unroll
            for (int nt = 0; nt < 4; nt++) {
                int jkey = jt * 64 + nt * 16 + l15;
                #pragma unroll
                for (int r = 0; r < 4; r++)
                    if (jkey > qbase + r) sarr[nt][r] = -INFINITY;
            }
        }

        // ---- row max + defer-max rescale (T13) ----
        float pm[4];
        #pragma unroll
        for (int r = 0; r < 4; r++) {
            float m = fmaxf(fmaxf(sarr[0][r], sarr[1][r]), fmaxf(sarr[2][r], sarr[3][r]));
            m = fmaxf(m, __shfl_xor(m, 1));
            m = fmaxf(m, __shfl_xor(m, 2));
            m = fmaxf(m, __shfl_xor(m, 4));
            m = fmaxf(m, __shfl_xor(m, 8));
            pm[r] = m;
        }
        float grow = fmaxf(fmaxf(pm[0] - mr[0], pm[1] - mr[1]),
                           fmaxf(pm[2] - mr[2], pm[3] - mr[3]));
        if (__any(grow > 8.0f)) {
            #pragma unroll
            for (int r = 0; r < 4; r++) {
                float mn = fmaxf(mr[r], pm[r]);
                float a  = exp2f(mr[r] - mn);
                mr[r] = mn;
                lr[r] *= a;
                #pragma unroll
                for (int nt = 0; nt < 4; nt++) oa[nt][r] *= a;
            }
        }

        // ---- P = exp2(S - m), partial rowsum, packed bf16 store to Ps ----
        u16* pw = Ps[wave];
        float lp[4] = {0.f, 0.f, 0.f, 0.f};
        #pragma unroll
        for (int nt = 0; nt < 4; nt++) {
            float p0 = exp2f(sarr[nt][0] - mr[0]);
            float p1 = exp2f(sarr[nt][1] - mr[1]);
            float p2 = exp2f(sarr[nt][2] - mr[2]);
            float p3 = exp2f(sarr[nt][3] - mr[3]);
            lp[0] += p0; lp[1] += p1; lp[2] += p2; lp[3] += p3;
            unsigned wlo = cvt_pk_bf16(p0, p1);
            unsigned whi = cvt_pk_bf16(p2, p3);
            const int gb = nt * 2 + (l15 >> 3);
            const int r0 = lg * 4;
            pw[(r0 + 0) * 64 + ((gb ^ ((r0 + 0) & 7))) * 8 + l7] = (u16)wlo;
            pw[(r0 + 1) * 64 + ((gb ^ ((r0 + 1) & 7))) * 8 + l7] = (u16)(wlo >> 16);
            pw[(r0 + 2) * 64 + ((gb ^ ((r0 + 2) & 7))) * 8 + l7] = (u16)whi;
            pw[(r0 + 3) * 64 + ((gb ^ ((r0 + 3) & 7))) * 8 + l7] = (u16)(whi >> 16);
        }
        #pragma unroll
        for (int r = 0; r < 4; r++) lr[r] += lp[r];

        // ---- read P fragments back (same wave; lgkmcnt ordered) ----
        short8 pf[2];
        #pragma unroll
        for (int kc = 0; kc < 2; kc++)
            pf[kc] = *(const short8*)&pw[l15 * 64 + ((kc * 4 + lg) ^ l7) * 8];

        // ---- PV (swizzled V^T reads) ----
        #pragma unroll
        for (int nt = 0; nt < 4; nt++) {
            #pragma unroll
            for (int kc = 0; kc < 2; kc++) {
                const short8 vfrag = *(const short8*)
                    &Vs[cur][(nt * 16 + l15) * 64 + ((kc * 4 + lg) ^ l7) * 8];
                oa[nt] = __builtin_amdgcn_mfma_f32_16x16x32_bf16(pf[kc], vfrag, oa[nt], 0, 0, 0);
            }
        }
    };

    stage(0, 0);
    __syncthreads();

    const int njt = qtb + 1;     // jt = 0..qtb
    for (int jt = 0; jt < njt; jt++) {
        const int cur = jt & 1;
        if (jt + 1 < njt) stage(cur ^ 1, (jt + 1) * 64);   // prefetch next tile

        flash_step(cur, jt, qtb, qfB, oB, mB, lB);          // big tile: always
        if (jt <= qta)
            flash_step(cur, jt, qta, qfA, oA, mA, lA);      // small tile: prefix

        __syncthreads();   // drains prefetch vmcnt + protects buffer reuse
    }

    // ---- epilogue: both Q-tiles ----
    const float hs = 1.0f + head_scale[h];
    auto epilogue = [&](int t0, float4v (&oa)[4], float (&lr)[4]) {
        #pragma unroll
        for (int r = 0; r < 4; r++) {
            float l = lr[r];
            l += __shfl_xor(l, 1);
            l += __shfl_xor(l, 2);
            l += __shfl_xor(l, 4);
            l += __shfl_xor(l, 8);
            const int q = t0 + wave * 16 + lg * 4 + r;
            const float f = hs / l;
            u16* op = out + ((size_t)(b * TT + q) * NN) + h * QKD + l15;
            #pragma unroll
            for (int nt = 0; nt < 4; nt++)
                op[nt * 16] = f2bf(oa[nt][r] * f);
        }
    };
    epilogue(t0b, oB, lB);
    epilogue(t0a, oA, lA);
}

// ---------------------------------------------------------------------------
extern "C" void kernel_launch(void* const* d_in, const int* in_sizes, int n_in,
                              void* d_out, int out_size, void* d_ws, size_t ws_size,
                              hipStream_t stream)
{
    const float* q          = (const float*)d_in[0];
    const float* kv         = (const float*)d_in[1];
    /* d_in[2] = causal mask -- handled analytically */
    const int*   qpos       = (const int*)d_in[3];
    const int*   kpos       = (const int*)d_in[4];
    const float* Wq         = (const float*)d_in[5];
    const float* bq         = (const float*)d_in[6];
    const float* Wk         = (const float*)d_in[7];
    const float* bk         = (const float*)d_in[8];
    const float* Wv         = (const float*)d_in[9];
    const float* bv         = (const float*)d_in[10];
    const float* q_scale    = (const float*)d_in[11];
    const float* k_scale    = (const float*)d_in[12];
    const float* head_scale = (const float*)d_in[13];
    const float* Wo         = (const float*)d_in[14];
    const float* bo         = (const float*)d_in[15];
    float* out = (float*)d_out;

    // workspace layout (bytes):
    //   [  0 MB, 16 MB)  qb    (M,K) bf16
    //   [ 16 MB, 32 MB)  kvb   (M,K) bf16
    //   [ 32 MB, 40 MB)  Wt    4 x (N,K) bf16 transposed: Wq,Wk,Wv,Wo
    //   [ 40 MB, 56 MB)  qh_b  (B,H,T,QK) bf16
    //   [ 56 MB, 72 MB)  kh_b  (B,H,T,QK) bf16
    //   [ 72 MB, 88 MB)  vt_b  (B,H,QK,T) bf16  <-- V stored transposed
    //   [ 88 MB,104 MB)  attn_b (B,T,N) bf16
    char* ws = (char*)d_ws;
    u16* qb     = (u16*)(ws);
    u16* kvb    = (u16*)(ws + (16u << 20));
    u16* Wt     = (u16*)(ws + (32u << 20));
    u16* qh_b   = (u16*)(ws + (40u << 20));
    u16* kh_b   = (u16*)(ws + (56u << 20));
    u16* vt_b   = (u16*)(ws + (72u << 20));
    u16* attn_b = (u16*)(ws + (88u << 20));

    // 1. cast activations to bf16
    acast_kernel<<<dim3(MM * DD / (256 * 4), 2), 256, 0, stream>>>(q, kv, qb, kvb);
    // 2. transpose+cast the four weight matrices
    wt_kernel<<<dim3(16, 16, 4), 256, 0, stream>>>(Wq, Wk, Wv, Wo, Wt);
    // 3. fused QKV projection (256x64 tile, 2 blocks/CU, even 6/CU grid)
    qkv_gemm<<<dim3(NN / 64, MM / 256, 3), 256, 0, stream>>>(
        qb, kvb, Wt, bq, bk, bv, qpos, kpos, q_scale, k_scale, qh_b, kh_b, vt_b);
    // 4. causal MFMA flash attention, paired complementary Q-tiles -> (B,T,N) bf16
    attn_mfma<<<dim3(TT / 128, HH, BB), 256, 0, stream>>>(qh_b, kh_b, vt_b, head_scale, attn_b);
    // 5. output projection (256x64 tile, even 2/CU grid) + bias -> fp32
    out_gemm<<<dim3(NN / 64, MM / 256), 256, 0, stream>>>(attn_b, Wt + (size_t)3 * KK * NN, bo, out);
}